// Round 2
// baseline (1688.509 us; speedup 1.0000x reference)
//
#include <hip/hip_runtime.h>
#include <hip/hip_bf16.h>

namespace {

constexpr int CB   = 32;            // batch
constexpr int CS   = 64;            // seq len
constexpr int CDIN = 256;           // encoder hidden
constexpr int CH   = 256;           // LSTM hidden / GAT feature
constexpr int CE   = 128;           // embedding dim
constexpr int CV   = 128;           // vocab
constexpr int CGH  = 64;            // per-head GAT dim
constexpr int CNH  = 4;             // heads
constexpr int CN   = 128;           // graph nodes (1 token + 127 intents)
constexpr int CDX  = CDIN + CE;     // 384 LSTM input
constexpr int CG   = 4 * CH;        // 1024 gates
constexpr int CM   = CB * CS;       // 2048 tokens

typedef _Float16 f16x2 __attribute__((ext_vector_type(2)));

__device__ __forceinline__ float leakyf(float x) { return x >= 0.f ? x : 0.2f * x; }
__device__ __forceinline__ float eluf(float x)   { return x > 0.f ? x : expm1f(x); }
__device__ __forceinline__ float sigmf(float x)  { return 1.f / (1.f + expf(-x)); }
__device__ __forceinline__ float wredf(float v) {
  #pragma unroll
  for (int off = 32; off; off >>= 1) v += __shfl_xor(v, off);
  return v;
}

// x[m, 0:256] = hidden[b,s,:]; x[m, 256:384] = (s==0 ? init : embedding[forced[b,s-1]])
__global__ void k_build_x(const float* __restrict__ hidden, const int* __restrict__ forced,
                          const float* __restrict__ emb, const float* __restrict__ initt,
                          float* __restrict__ x) {
  int idx = blockIdx.x * 256 + threadIdx.x;
  if (idx >= CM * CDX) return;
  int m = idx / CDX, d = idx - m * CDX;
  float v;
  if (d < CDIN) {
    v = hidden[m * CDIN + d];
  } else {
    int e = d - CDIN;
    v = (m % CS == 0) ? initt[e] : emb[forced[m - 1] * CE + e];
  }
  x[idx] = v;
}

// out[C][R] = in[R][C]^T
__global__ void k_transpose(const float* __restrict__ in, float* __restrict__ out,
                            int R, int C) {
  int idx = blockIdx.x * 256 + threadIdx.x;
  if (idx >= R * C) return;
  int c = idx / R, r = idx - c * R;
  out[idx] = in[r * C + c];
}

// Pack W_hh [1024 g][256 k] fp32 -> Wp[q][g] = half2(W_hh[g][2q], W_hh[g][2q+1])
// 16 blocks x 256 threads; LDS tile transpose (pad 257 to break bank conflicts)
__global__ void k_whh_pack(const float* __restrict__ Whh, f16x2* __restrict__ Wp) {
  __shared__ float tile[64][257];
  int g0 = blockIdx.x * 64;
  for (int idx = threadIdx.x; idx < 64 * 256; idx += 256) {
    int gl = idx >> 8, kk = idx & 255;
    tile[gl][kk] = Whh[(g0 + gl) * CH + kk];
  }
  __syncthreads();
  for (int idx = threadIdx.x; idx < 128 * 64; idx += 256) {
    int q = idx >> 6, gl = idx & 63;
    f16x2 w = { (_Float16)tile[gl][2 * q], (_Float16)tile[gl][2 * q + 1] };
    Wp[q * CG + g0 + gl] = w;
  }
}

// hint[k][i][c] = intent[i] . Wh[k][:,c];  f1int/f2int[k][i] = hint . ah[k][0:64 / 64:128]
__global__ void k_hint(const float* __restrict__ intent, const float* __restrict__ Wh,
                       const float* __restrict__ ah, float* __restrict__ hint,
                       float* __restrict__ f1int, float* __restrict__ f2int) {
  int k = blockIdx.x / 127;
  int i = blockIdx.x % 127;
  int c = threadIdx.x;  // 64 threads
  float acc = 0.f;
  for (int d = 0; d < CH; ++d)
    acc += intent[i * CH + d] * Wh[(k * CH + d) * CGH + c];
  hint[(k * 128 + i) * CGH + c] = acc;
  float r1 = wredf(acc * ah[k * 128 + c]);
  float r2 = wredf(acc * ah[k * 128 + 64 + c]);
  if (c == 0) { f1int[k * 128 + i] = r1; f2int[k * 128 + i] = r2; }
}

// woao1[kk] = Wo[kk,:] . ao[0:256];  woao2[kk] = Wo[kk,:] . ao[256:512]
__global__ void k_woao(const float* __restrict__ Wo, const float* __restrict__ ao,
                       float* __restrict__ woao1, float* __restrict__ woao2) {
  int t = threadIdx.x;  // 512 threads
  if (t < CH) {
    float acc = 0.f;
    for (int c = 0; c < CH; ++c) acc += Wo[t * CH + c] * ao[c];
    woao1[t] = acc;
  } else {
    int tt = t - CH;
    float acc = 0.f;
    for (int c = 0; c < CH; ++c) acc += Wo[tt * CH + c] * ao[CH + c];
    woao2[tt] = acc;
  }
}

// xg[m,g] = x[m,:] . W_ihT[:,g] + b_ih[g] + b_hh[g]   (M=2048, K=384, N=1024)
__global__ void k_xg(const float* __restrict__ x, const float* __restrict__ WihT,
                     const float* __restrict__ bih, const float* __restrict__ bhh,
                     float* __restrict__ xg) {
  __shared__ float xs[8][CDX];
  int m0 = blockIdx.x * 8;
  int g = blockIdx.y * 256 + threadIdx.x;
  for (int idx = threadIdx.x; idx < 8 * CDX; idx += 256) {
    int r = idx / CDX, kk = idx - r * CDX;
    xs[r][kk] = x[(m0 + r) * CDX + kk];
  }
  __syncthreads();
  float bias = bih[g] + bhh[g];
  float acc[8];
  #pragma unroll
  for (int r = 0; r < 8; ++r) acc[r] = bias;
  #pragma unroll 4
  for (int kk = 0; kk < CDX; ++kk) {
    float w = WihT[kk * CG + g];
    #pragma unroll
    for (int r = 0; r < 8; ++r) acc[r] += w * xs[r][kk];
  }
  #pragma unroll
  for (int r = 0; r < 8; ++r) xg[(m0 + r) * CG + g] = acc[r];
}

// One block per batch element; 512 threads, 2 gates each (g and g+512).
// 96/128 half2 weight-pairs per gate live in VGPRs; 32 streamed from L2 per step.
__global__ __launch_bounds__(512, 2) void k_lstm2(const float* __restrict__ xg,
                                                  const f16x2* __restrict__ Wp,
                                                  float* __restrict__ lo) {
  int b = blockIdx.x;
  int tt = threadIdx.x;
  int g0 = tt, g1 = tt + 512;
  __shared__ float gbuf[CG];
  __shared__ f16x2 hsh2[CH / 2];
  _Float16* hsh = (_Float16*)hsh2;

  f16x2 wr0[96], wr1[96];
  #pragma unroll
  for (int q = 0; q < 96; ++q) {
    wr0[q] = Wp[q * CG + g0];
    wr1[q] = Wp[q * CG + g1];
  }
  if (tt < CH / 2) { f16x2 z = {(_Float16)0.f, (_Float16)0.f}; hsh2[tt] = z; }
  float c = 0.f;
  __syncthreads();

  const float* xgb = xg + b * CS * CG;
  float nx0 = xgb[g0], nx1 = xgb[g1];
  for (int t = 0; t < CS; ++t) {
    asm volatile("" ::: "memory");   // keep streamed weight loads inside the loop
    float acc0 = nx0, acc1 = nx1;
    int tn = (t + 1 < CS) ? t + 1 : t;
    nx0 = xgb[tn * CG + g0];
    nx1 = xgb[tn * CG + g1];
    #pragma unroll
    for (int q = 0; q < 96; ++q) {
      f16x2 hq = hsh2[q];
      acc0 = __builtin_amdgcn_fdot2(wr0[q], hq, acc0, false);
      acc1 = __builtin_amdgcn_fdot2(wr1[q], hq, acc1, false);
    }
    #pragma unroll
    for (int q = 96; q < 128; ++q) {
      f16x2 hq = hsh2[q];
      acc0 = __builtin_amdgcn_fdot2(Wp[q * CG + g0], hq, acc0, false);
      acc1 = __builtin_amdgcn_fdot2(Wp[q * CG + g1], hq, acc1, false);
    }
    gbuf[g0] = acc0;
    gbuf[g1] = acc1;
    __syncthreads();
    if (tt < CH) {
      float gi = gbuf[tt], gf = gbuf[CH + tt], gg = gbuf[2 * CH + tt], go = gbuf[3 * CH + tt];
      c = sigmf(gf) * c + sigmf(gi) * tanhf(gg);
      float h = sigmf(go) * tanhf(c);
      hsh[tt] = (_Float16)h;
      lo[(b * CS + t) * CH + tt] = h;
    }
    __syncthreads();
  }
}

// per (b,head): wS[i] = sum_{j>=1,adj} w_ij ; U[i][c] = sum_j w_ij * hint[j][c]   (rows i=1..127)
__global__ void k_U(const float* __restrict__ hint, const float* __restrict__ f1int,
                    const float* __restrict__ f2int, const int* __restrict__ adj,
                    float* __restrict__ U, float* __restrict__ wS) {
  int b = blockIdx.x >> 2, k = blockIdx.x & 3;
  int grp = threadIdx.x >> 6, c = threadIdx.x & 63;
  __shared__ float wbuf[4][128];
  const int adjb = b * CN * CN;
  for (int i = 1 + grp; i < 128; i += 4) {
    float f1 = f1int[k * 128 + (i - 1)];
    int j1 = 1 + c, j2 = 65 + c;
    float w1 = 0.f, w2 = 0.f;
    if (adj[adjb + i * CN + j1]) w1 = expf(leakyf(f1 + f2int[k * 128 + j1 - 1]));
    if (j2 < 128 && adj[adjb + i * CN + j2]) w2 = expf(leakyf(f1 + f2int[k * 128 + j2 - 1]));
    wbuf[grp][c] = w1;
    wbuf[grp][64 + c] = w2;              // slot 127 (c=63) = 0
    float rs = wredf(w1 + w2);
    float acc = 0.f;
    for (int jj = 0; jj < 127; ++jj)     // jj = j-1
      acc += wbuf[grp][jj] * hint[(k * 128 + jj) * CGH + c];
    if (c == 0) wS[(b * 4 + k) * 128 + i] = rs;
    U[((b * 4 + k) * 128 + i) * CGH + c] = acc;
  }
}

// htok[m, k*64+c] = lo[m,:] . Wh[k][:,c];  f1tok/f2tok[m,k] reductions
__global__ void k_htok(const float* __restrict__ lo, const float* __restrict__ Wh,
                       const float* __restrict__ ah, float* __restrict__ htok,
                       float* __restrict__ f1tok, float* __restrict__ f2tok) {
  __shared__ float ls[8][CH];
  int m0 = blockIdx.x * 8;
  int tid = threadIdx.x;
  int k = tid >> 6, c = tid & 63;
  for (int idx = tid; idx < 8 * CH; idx += 256) {
    int r = idx >> 8, d = idx & 255;
    ls[r][d] = lo[(m0 + r) * CH + d];
  }
  __syncthreads();
  float acc[8];
  #pragma unroll
  for (int r = 0; r < 8; ++r) acc[r] = 0.f;
  #pragma unroll 4
  for (int d = 0; d < CH; ++d) {
    float w = Wh[(k * CH + d) * CGH + c];
    #pragma unroll
    for (int r = 0; r < 8; ++r) acc[r] += w * ls[r][d];
  }
  float a1 = ah[k * 128 + c], a2 = ah[k * 128 + 64 + c];
  #pragma unroll
  for (int r = 0; r < 8; ++r) {
    htok[(m0 + r) * CH + tid] = acc[r];
    float r1 = wredf(acc[r] * a1);
    float r2 = wredf(acc[r] * a2);
    if (c == 0) { f1tok[(m0 + r) * CNH + k] = r1; f2tok[(m0 + r) * CNH + k] = r2; }
  }
}

// Fully fused per-token kernel: layer-1 rows (rank-1 update + row 0), layer-2 row 0
// via linearity, residual, logits. One block per token m, 256 threads.
__global__ void k_perm(const float* __restrict__ lo, const float* __restrict__ htok,
                       const float* __restrict__ f1tok, const float* __restrict__ f2tok,
                       const float* __restrict__ hint, const float* __restrict__ f1int,
                       const float* __restrict__ f2int, const float* __restrict__ U,
                       const float* __restrict__ wS, const float* __restrict__ woao1,
                       const float* __restrict__ woao2, const int* __restrict__ adj,
                       const float* __restrict__ Wo, const float* __restrict__ Wl,
                       const float* __restrict__ bl, const int* __restrict__ seq_lens,
                       float* __restrict__ out) {
  int m = blockIdx.x;
  int b = m >> 6, s = m & 63;
  int tid = threadIdx.x;
  int k = tid >> 6, c = tid & 63;

  __shared__ __hip_bfloat16 x1[CN][CH];  // 64 KB, layer-1 output (elu'd, heads concat)
  __shared__ float w0[CNH][CN];
  __shared__ float f22[CN];
  __shared__ float w2[CN];
  __shared__ float ybuf[CH];
  __shared__ float gbuf[CH];
  __shared__ float f12s, den2s;

  const int adjb = b * CN * CN;
  float ht  = htok[m * CH + tid];     // htok[m, k*64+c]
  float f1t = f1tok[m * CNH + k];
  float f2t = f2tok[m * CNH + k];

  // ---- layer-1 rows 1..127: rank-1 correction of precomputed (U, wS)
  for (int i = 1; i < CN; ++i) {
    float t0 = 0.f;
    if (adj[adjb + i * CN]) t0 = expf(leakyf(f1int[k * 128 + i - 1] + f2t));
    float den = wS[(b * 4 + k) * 128 + i] + t0;
    float val = (U[((b * 4 + k) * 128 + i) * CGH + c] + t0 * ht) / den;
    x1[i][tid] = __float2bfloat16(eluf(val));
  }

  // ---- layer-1 row 0 (full, per token)
  {
    int j1 = c, j2 = c + 64;
    float e1 = leakyf(f1t + (j1 == 0 ? f2t : f2int[k * 128 + j1 - 1]));
    float wj1 = adj[adjb + j1] ? expf(e1) : 0.f;
    float e2 = leakyf(f1t + f2int[k * 128 + j2 - 1]);
    float wj2 = adj[adjb + j2] ? expf(e2) : 0.f;
    w0[k][j1] = wj1;
    w0[k][j2] = wj2;
    float den0 = wredf(wj1 + wj2);          // all lanes hold row sum
    float acc = w0[k][0] * ht;              // in-wave LDS RAW: safe
    for (int j = 1; j < CN; ++j) acc += w0[k][j] * hint[(k * 128 + j - 1) * CGH + c];
    x1[0][tid] = __float2bfloat16(eluf(acc / den0));
  }
  __syncthreads();

  // ---- layer-2 attention scalars: f2_2[j] = x1[j,:] . (Wo@ao2); f1_2 = x1[0,:] . (Wo@ao1)
  {
    float wa0 = woao2[c], wa1 = woao2[64 + c], wa2 = woao2[128 + c], wa3 = woao2[192 + c];
    for (int j = k; j < CN; j += 4) {
      float p = __bfloat162float(x1[j][c]) * wa0
              + __bfloat162float(x1[j][64 + c]) * wa1
              + __bfloat162float(x1[j][128 + c]) * wa2
              + __bfloat162float(x1[j][192 + c]) * wa3;
      p = wredf(p);
      if (c == 0) f22[j] = p;
    }
    if (k == 0) {
      float p = __bfloat162float(x1[0][c]) * woao1[c]
              + __bfloat162float(x1[0][64 + c]) * woao1[64 + c]
              + __bfloat162float(x1[0][128 + c]) * woao1[128 + c]
              + __bfloat162float(x1[0][192 + c]) * woao1[192 + c];
      p = wredf(p);
      if (c == 0) f12s = p;
    }
  }
  __syncthreads();

  // ---- att2 row 0
  if (tid < CN) {
    float e = leakyf(f12s + f22[tid]);
    w2[tid] = adj[adjb + tid] ? expf(e) : 0.f;
  }
  __syncthreads();
  if (k == 0) {
    float v = wredf(w2[c] + w2[c + 64]);
    if (c == 0) den2s = v;
  }
  // y[col] = sum_j w2[j] * x1[j][col]   (undivided)
  float yacc = 0.f;
  for (int j = 0; j < CN; ++j) yacc += w2[j] * __bfloat162float(x1[j][tid]);
  ybuf[tid] = yacc;
  __syncthreads();

  // hp2[col] = (y @ Wo)[col] / den2 ; g = elu(hp2) + lo[m]
  float hacc = 0.f;
  #pragma unroll 4
  for (int kk = 0; kk < CH; ++kk) hacc += ybuf[kk] * Wo[kk * CH + tid];
  float g = eluf(hacc / den2s) + lo[m * CH + tid];
  gbuf[tid] = g;
  __syncthreads();

  // logits
  if (tid < CV) {
    float acc = bl[tid];
    #pragma unroll 4
    for (int cc = 0; cc < CH; ++cc) acc += gbuf[cc] * Wl[cc * CV + tid];
    out[m * CV + tid] = (s < seq_lens[b]) ? acc : 0.f;
  }
}

}  // namespace

extern "C" void kernel_launch(void* const* d_in, const int* in_sizes, int n_in,
                              void* d_out, int out_size, void* d_ws, size_t ws_size,
                              hipStream_t stream) {
  const float* hidden   = (const float*)d_in[0];
  const int*   seq_lens = (const int*)d_in[1];
  const int*   forced   = (const int*)d_in[2];
  const int*   adj      = (const int*)d_in[3];
  const float* intent   = (const float*)d_in[4];
  const float* emb      = (const float*)d_in[5];
  const float* initt    = (const float*)d_in[6];
  const float* W_ih     = (const float*)d_in[7];
  const float* W_hh     = (const float*)d_in[8];
  const float* b_ih     = (const float*)d_in[9];
  const float* b_hh     = (const float*)d_in[10];
  const float* Wh       = (const float*)d_in[11];
  const float* ah       = (const float*)d_in[12];
  const float* Wo       = (const float*)d_in[13];
  const float* ao       = (const float*)d_in[14];
  const float* Wl       = (const float*)d_in[15];
  const float* bl       = (const float*)d_in[16];
  float* out = (float*)d_out;

  float* ws    = (float*)d_ws;
  float* x     = ws;                       // 2048*384
  float* WihT  = x + CM * CDX;             // 384*1024
  float* WpF   = WihT + CDX * CG;          // 128*1024 f16x2 = 131072 float slots
  float* xg    = WpF + (CH / 2) * CG;      // 2048*1024
  float* lo    = xg + CM * CG;             // 2048*256
  float* htok  = lo + CM * CH;             // 2048*256
  float* f1tok = htok + CM * CH;           // 2048*4
  float* f2tok = f1tok + CM * CNH;         // 2048*4
  float* hint  = f2tok + CM * CNH;         // 4*128*64
  float* f1int = hint + CNH * 128 * CGH;   // 4*128
  float* f2int = f1int + CNH * 128;        // 4*128
  float* U     = f2int + CNH * 128;        // 32*4*128*64
  float* wS    = U + CB * CNH * 128 * CGH; // 32*4*128
  float* woao1 = wS + CB * CNH * 128;      // 256
  float* woao2 = woao1 + CH;               // 256
  f16x2* Wp    = (f16x2*)WpF;

  k_build_x<<<(CM * CDX + 255) / 256, 256, 0, stream>>>(hidden, forced, emb, initt, x);
  k_transpose<<<(CG * CDX + 255) / 256, 256, 0, stream>>>(W_ih, WihT, CG, CDX);
  k_whh_pack<<<CG / 64, 256, 0, stream>>>(W_hh, Wp);
  k_hint<<<CNH * 127, 64, 0, stream>>>(intent, Wh, ah, hint, f1int, f2int);
  k_woao<<<1, 512, 0, stream>>>(Wo, ao, woao1, woao2);
  k_xg<<<dim3(CM / 8, CG / 256), 256, 0, stream>>>(x, WihT, b_ih, b_hh, xg);
  k_U<<<CB * CNH, 256, 0, stream>>>(hint, f1int, f2int, adj, U, wS);
  k_lstm2<<<CB, 512, 0, stream>>>(xg, Wp, lo);
  k_htok<<<CM / 8, 256, 0, stream>>>(lo, Wh, ah, htok, f1tok, f2tok);
  k_perm<<<CM, 256, 0, stream>>>(lo, htok, f1tok, f2tok, hint, f1int, f2int,
                                 U, wS, woao1, woao2, adj, Wo, Wl, bl, seq_lens, out);
}

// Round 3
// 1052.800 us; speedup vs baseline: 1.6038x; 1.6038x over previous
//
#include <hip/hip_runtime.h>
#include <hip/hip_bf16.h>

namespace {

constexpr int CB   = 32;            // batch
constexpr int CS   = 64;            // seq len
constexpr int CDIN = 256;           // encoder hidden
constexpr int CH   = 256;           // LSTM hidden / GAT feature
constexpr int CE   = 128;           // embedding dim
constexpr int CV   = 128;           // vocab
constexpr int CGH  = 64;            // per-head GAT dim
constexpr int CNH  = 4;             // heads
constexpr int CN   = 128;           // graph nodes (1 token + 127 intents)
constexpr int CDX  = CDIN + CE;     // 384 LSTM input
constexpr int CG   = 4 * CH;        // 1024 gates
constexpr int CM   = CB * CS;       // 2048 tokens
constexpr int QREG = 96;            // weight half2-pairs kept in VGPRs per gate
constexpr int QTL  = 128 - QREG;    // 32 streamed pairs per gate

typedef _Float16 f16x2 __attribute__((ext_vector_type(2)));
typedef _Float16 f16x8 __attribute__((ext_vector_type(8)));
typedef float    f32x4 __attribute__((ext_vector_type(4)));

__device__ __forceinline__ float leakyf(float x) { return x >= 0.f ? x : 0.2f * x; }
__device__ __forceinline__ float eluf(float x)   { return x > 0.f ? x : expm1f(x); }
__device__ __forceinline__ float sigmf(float x)  { return 1.f / (1.f + expf(-x)); }
__device__ __forceinline__ float wredf(float v) {
  #pragma unroll
  for (int off = 32; off; off >>= 1) v += __shfl_xor(v, off);
  return v;
}

// x[m, 0:256] = hidden[b,s,:]; x[m, 256:384] = (s==0 ? init : embedding[forced[b,s-1]])
__global__ void k_build_x(const float* __restrict__ hidden, const int* __restrict__ forced,
                          const float* __restrict__ emb, const float* __restrict__ initt,
                          float* __restrict__ x) {
  int idx = blockIdx.x * 256 + threadIdx.x;
  if (idx >= CM * CDX) return;
  int m = idx / CDX, d = idx - m * CDX;
  float v;
  if (d < CDIN) {
    v = hidden[m * CDIN + d];
  } else {
    int e = d - CDIN;
    v = (m % CS == 0) ? initt[e] : emb[forced[m - 1] * CE + e];
  }
  x[idx] = v;
}

// Pack W_hh [1024 g][256 k] fp32 -> Wp[q][g] (q<96, gate-minor for coalesced reg fill)
// and Wt[g][j] (j=q-96, gate-major so each thread's tail is contiguous f16x8 chunks).
__global__ void k_whh_pack(const float* __restrict__ Whh, f16x2* __restrict__ Wp,
                           f16x2* __restrict__ Wt) {
  __shared__ float tile[64][257];
  int g0 = blockIdx.x * 64;
  for (int idx = threadIdx.x; idx < 64 * 256; idx += 256) {
    int gl = idx >> 8, kk = idx & 255;
    tile[gl][kk] = Whh[(g0 + gl) * CH + kk];
  }
  __syncthreads();
  for (int idx = threadIdx.x; idx < 128 * 64; idx += 256) {
    int q = idx >> 6, gl = idx & 63;
    f16x2 w = { (_Float16)tile[gl][2 * q], (_Float16)tile[gl][2 * q + 1] };
    if (q < QREG) Wp[q * CG + g0 + gl] = w;
    else          Wt[(g0 + gl) * QTL + (q - QREG)] = w;
  }
}

// hint[k][i][c] = intent[i] . Wh[k][:,c];  f1int/f2int[k][i] = hint . ah[k][0:64 / 64:128]
__global__ void k_hint(const float* __restrict__ intent, const float* __restrict__ Wh,
                       const float* __restrict__ ah, float* __restrict__ hint,
                       float* __restrict__ f1int, float* __restrict__ f2int) {
  int k = blockIdx.x / 127;
  int i = blockIdx.x % 127;
  int c = threadIdx.x;  // 64 threads
  float acc = 0.f;
  for (int d = 0; d < CH; ++d)
    acc += intent[i * CH + d] * Wh[(k * CH + d) * CGH + c];
  hint[(k * 128 + i) * CGH + c] = acc;
  float r1 = wredf(acc * ah[k * 128 + c]);
  float r2 = wredf(acc * ah[k * 128 + 64 + c]);
  if (c == 0) { f1int[k * 128 + i] = r1; f2int[k * 128 + i] = r2; }
}

// woao1[kk] = Wo[kk,:] . ao[0:256];  woao2[kk] = Wo[kk,:] . ao[256:512]
__global__ void k_woao(const float* __restrict__ Wo, const float* __restrict__ ao,
                       float* __restrict__ woao1, float* __restrict__ woao2) {
  int t = threadIdx.x;  // 512 threads
  if (t < CH) {
    float acc = 0.f;
    for (int c = 0; c < CH; ++c) acc += Wo[t * CH + c] * ao[c];
    woao1[t] = acc;
  } else {
    int tt = t - CH;
    float acc = 0.f;
    for (int c = 0; c < CH; ++c) acc += Wo[tt * CH + c] * ao[CH + c];
    woao2[tt] = acc;
  }
}

// xg[m,g] = x[m,:] . W_ih[g,:] + b_ih[g] + b_hh[g]
// 256 blocks (8 m each), 256 threads (4 gates each), float4 everywhere.
__global__ void k_xg2(const float* __restrict__ x, const float* __restrict__ Wih,
                      const float* __restrict__ bih, const float* __restrict__ bhh,
                      float* __restrict__ xg) {
  __shared__ f32x4 xs[8][CDX / 4];  // 12 KB
  int m0 = blockIdx.x * 8;
  int tid = threadIdx.x;
  for (int idx = tid; idx < 8 * (CDX / 4); idx += 256) {
    int r = idx / (CDX / 4), q = idx - r * (CDX / 4);
    xs[r][q] = ((const f32x4*)x)[(m0 + r) * (CDX / 4) + q];
  }
  __syncthreads();
  int g0 = tid * 4;
  float acc[8][4];
  #pragma unroll
  for (int r = 0; r < 8; ++r)
    #pragma unroll
    for (int j = 0; j < 4; ++j) acc[r][j] = 0.f;
  const f32x4* w0 = (const f32x4*)(Wih + (g0 + 0) * CDX);
  const f32x4* w1 = (const f32x4*)(Wih + (g0 + 1) * CDX);
  const f32x4* w2 = (const f32x4*)(Wih + (g0 + 2) * CDX);
  const f32x4* w3 = (const f32x4*)(Wih + (g0 + 3) * CDX);
  #pragma unroll 2
  for (int q = 0; q < CDX / 4; ++q) {
    f32x4 wa = w0[q], wb = w1[q], wc = w2[q], wd = w3[q];
    #pragma unroll
    for (int r = 0; r < 8; ++r) {
      f32x4 xv = xs[r][q];
      acc[r][0] += wa.x * xv.x + wa.y * xv.y + wa.z * xv.z + wa.w * xv.w;
      acc[r][1] += wb.x * xv.x + wb.y * xv.y + wb.z * xv.z + wb.w * xv.w;
      acc[r][2] += wc.x * xv.x + wc.y * xv.y + wc.z * xv.z + wc.w * xv.w;
      acc[r][3] += wd.x * xv.x + wd.y * xv.y + wd.z * xv.z + wd.w * xv.w;
    }
  }
  f32x4 bias = { bih[g0] + bhh[g0], bih[g0 + 1] + bhh[g0 + 1],
                 bih[g0 + 2] + bhh[g0 + 2], bih[g0 + 3] + bhh[g0 + 3] };
  #pragma unroll
  for (int r = 0; r < 8; ++r) {
    f32x4 st = { acc[r][0] + bias.x, acc[r][1] + bias.y,
                 acc[r][2] + bias.z, acc[r][3] + bias.w };
    ((f32x4*)xg)[((m0 + r) * CG + g0) / 4] = st;
  }
}

// One block per batch element; 512 threads, 2 gates each (g and g+512).
// 96/128 weight-pairs per gate in VGPRs (launch_bounds(512,1): cap 512, ~230 used);
// 32-pair tail streamed as f16x8 from gate-major Wt; h read as uniform ds_read_b128.
__global__ __launch_bounds__(512, 1) void k_lstm3(const float* __restrict__ xg,
                                                  const f16x2* __restrict__ Wp,
                                                  const f16x2* __restrict__ Wt,
                                                  float* __restrict__ lo) {
  int b = blockIdx.x;
  int tt = threadIdx.x;
  int g0 = tt, g1 = tt + 512;
  __shared__ float gbuf[CG];
  __shared__ f16x8 hsh8[CH / 8];    // 256 h as fp16, 16B-aligned
  _Float16* hsh = (_Float16*)hsh8;

  f16x2 w0[QREG], w1[QREG];
  #pragma unroll
  for (int q = 0; q < QREG; ++q) {
    w0[q] = Wp[q * CG + g0];
    w1[q] = Wp[q * CG + g1];
  }
  const f16x8* wt0 = (const f16x8*)(Wt + g0 * QTL);  // 8 chunks of 4 pairs
  const f16x8* wt1 = (const f16x8*)(Wt + g1 * QTL);

  if (tt < CH) hsh[tt] = (_Float16)0.f;
  float c = 0.f;
  __syncthreads();

  const float* xgb = xg + b * CS * CG;
  float nx0 = xgb[g0], nx1 = xgb[g1];
  for (int t = 0; t < CS; ++t) {
    asm volatile("" ::: "memory");   // keep tail-weight loads inside the loop
    float acc0 = nx0, acc1 = nx1;
    int tn = (t + 1 < CS) ? t + 1 : t;
    nx0 = xgb[tn * CG + g0];
    nx1 = xgb[tn * CG + g1];
    // register-resident portion: q = 0..95 (h chunks 0..23)
    #pragma unroll
    for (int jc = 0; jc < QREG / 4; ++jc) {
      f16x8 hv = hsh8[jc];
      f16x2 ha = __builtin_shufflevector(hv, hv, 0, 1);
      f16x2 hb = __builtin_shufflevector(hv, hv, 2, 3);
      f16x2 hc = __builtin_shufflevector(hv, hv, 4, 5);
      f16x2 hd = __builtin_shufflevector(hv, hv, 6, 7);
      acc0 = __builtin_amdgcn_fdot2(w0[4 * jc + 0], ha, acc0, false);
      acc0 = __builtin_amdgcn_fdot2(w0[4 * jc + 1], hb, acc0, false);
      acc0 = __builtin_amdgcn_fdot2(w0[4 * jc + 2], hc, acc0, false);
      acc0 = __builtin_amdgcn_fdot2(w0[4 * jc + 3], hd, acc0, false);
      acc1 = __builtin_amdgcn_fdot2(w1[4 * jc + 0], ha, acc1, false);
      acc1 = __builtin_amdgcn_fdot2(w1[4 * jc + 1], hb, acc1, false);
      acc1 = __builtin_amdgcn_fdot2(w1[4 * jc + 2], hc, acc1, false);
      acc1 = __builtin_amdgcn_fdot2(w1[4 * jc + 3], hd, acc1, false);
    }
    // streamed tail: q = 96..127 (h chunks 24..31)
    #pragma unroll
    for (int jc = 0; jc < QTL / 4; ++jc) {
      f16x8 hv = hsh8[QREG / 4 + jc];
      f16x8 wa = wt0[jc];
      f16x8 wb = wt1[jc];
      f16x2 ha = __builtin_shufflevector(hv, hv, 0, 1);
      f16x2 hb = __builtin_shufflevector(hv, hv, 2, 3);
      f16x2 hc = __builtin_shufflevector(hv, hv, 4, 5);
      f16x2 hd = __builtin_shufflevector(hv, hv, 6, 7);
      acc0 = __builtin_amdgcn_fdot2(__builtin_shufflevector(wa, wa, 0, 1), ha, acc0, false);
      acc0 = __builtin_amdgcn_fdot2(__builtin_shufflevector(wa, wa, 2, 3), hb, acc0, false);
      acc0 = __builtin_amdgcn_fdot2(__builtin_shufflevector(wa, wa, 4, 5), hc, acc0, false);
      acc0 = __builtin_amdgcn_fdot2(__builtin_shufflevector(wa, wa, 6, 7), hd, acc0, false);
      acc1 = __builtin_amdgcn_fdot2(__builtin_shufflevector(wb, wb, 0, 1), ha, acc1, false);
      acc1 = __builtin_amdgcn_fdot2(__builtin_shufflevector(wb, wb, 2, 3), hb, acc1, false);
      acc1 = __builtin_amdgcn_fdot2(__builtin_shufflevector(wb, wb, 4, 5), hc, acc1, false);
      acc1 = __builtin_amdgcn_fdot2(__builtin_shufflevector(wb, wb, 6, 7), hd, acc1, false);
    }
    gbuf[g0] = acc0;
    gbuf[g1] = acc1;
    __syncthreads();
    if (tt < CH) {
      float gi = gbuf[tt], gf = gbuf[CH + tt], gg = gbuf[2 * CH + tt], go = gbuf[3 * CH + tt];
      c = sigmf(gf) * c + sigmf(gi) * tanhf(gg);
      float h = sigmf(go) * tanhf(c);
      hsh[tt] = (_Float16)h;
      lo[(b * CS + t) * CH + tt] = h;
    }
    __syncthreads();
  }
}

// per (b,head): wS[i] = sum_{j>=1,adj} w_ij ; U[i][c] = sum_j w_ij * hint[j][c]   (rows i=1..127)
__global__ void k_U(const float* __restrict__ hint, const float* __restrict__ f1int,
                    const float* __restrict__ f2int, const int* __restrict__ adj,
                    float* __restrict__ U, float* __restrict__ wS) {
  int b = blockIdx.x >> 2, k = blockIdx.x & 3;
  int grp = threadIdx.x >> 6, c = threadIdx.x & 63;
  __shared__ float wbuf[4][128];
  const int adjb = b * CN * CN;
  for (int i = 1 + grp; i < 128; i += 4) {
    float f1 = f1int[k * 128 + (i - 1)];
    int j1 = 1 + c, j2 = 65 + c;
    float w1 = 0.f, w2 = 0.f;
    if (adj[adjb + i * CN + j1]) w1 = expf(leakyf(f1 + f2int[k * 128 + j1 - 1]));
    if (j2 < 128 && adj[adjb + i * CN + j2]) w2 = expf(leakyf(f1 + f2int[k * 128 + j2 - 1]));
    wbuf[grp][c] = w1;
    wbuf[grp][64 + c] = w2;              // slot 127 (c=63) = 0
    float rs = wredf(w1 + w2);
    float acc = 0.f;
    for (int jj = 0; jj < 127; ++jj)     // jj = j-1
      acc += wbuf[grp][jj] * hint[(k * 128 + jj) * CGH + c];
    if (c == 0) wS[(b * 4 + k) * 128 + i] = rs;
    U[((b * 4 + k) * 128 + i) * CGH + c] = acc;
  }
}

// htok[m, k*64+c] = lo[m,:] . Wh[k][:,c];  f1tok/f2tok[m,k] reductions
__global__ void k_htok(const float* __restrict__ lo, const float* __restrict__ Wh,
                       const float* __restrict__ ah, float* __restrict__ htok,
                       float* __restrict__ f1tok, float* __restrict__ f2tok) {
  __shared__ float ls[8][CH];
  int m0 = blockIdx.x * 8;
  int tid = threadIdx.x;
  int k = tid >> 6, c = tid & 63;
  for (int idx = tid; idx < 8 * CH; idx += 256) {
    int r = idx >> 8, d = idx & 255;
    ls[r][d] = lo[(m0 + r) * CH + d];
  }
  __syncthreads();
  float acc[8];
  #pragma unroll
  for (int r = 0; r < 8; ++r) acc[r] = 0.f;
  #pragma unroll 4
  for (int d = 0; d < CH; ++d) {
    float w = Wh[(k * CH + d) * CGH + c];
    #pragma unroll
    for (int r = 0; r < 8; ++r) acc[r] += w * ls[r][d];
  }
  float a1 = ah[k * 128 + c], a2 = ah[k * 128 + 64 + c];
  #pragma unroll
  for (int r = 0; r < 8; ++r) {
    htok[(m0 + r) * CH + tid] = acc[r];
    float r1 = wredf(acc[r] * a1);
    float r2 = wredf(acc[r] * a2);
    if (c == 0) { f1tok[(m0 + r) * CNH + k] = r1; f2tok[(m0 + r) * CNH + k] = r2; }
  }
}

// Fully fused per-token kernel: layer-1 rows (rank-1 update + row 0), layer-2 row 0
// via linearity, residual, logits. One block per token m, 256 threads.
__global__ void k_perm(const float* __restrict__ lo, const float* __restrict__ htok,
                       const float* __restrict__ f1tok, const float* __restrict__ f2tok,
                       const float* __restrict__ hint, const float* __restrict__ f1int,
                       const float* __restrict__ f2int, const float* __restrict__ U,
                       const float* __restrict__ wS, const float* __restrict__ woao1,
                       const float* __restrict__ woao2, const int* __restrict__ adj,
                       const float* __restrict__ Wo, const float* __restrict__ Wl,
                       const float* __restrict__ bl, const int* __restrict__ seq_lens,
                       float* __restrict__ out) {
  int m = blockIdx.x;
  int b = m >> 6, s = m & 63;
  int tid = threadIdx.x;
  int k = tid >> 6, c = tid & 63;

  __shared__ __hip_bfloat16 x1[CN][CH];  // 64 KB, layer-1 output (elu'd, heads concat)
  __shared__ float w0[CNH][CN];
  __shared__ float f22[CN];
  __shared__ float w2[CN];
  __shared__ float ybuf[CH];
  __shared__ float gbuf[CH];
  __shared__ float f12s, den2s;

  const int adjb = b * CN * CN;
  float ht  = htok[m * CH + tid];     // htok[m, k*64+c]
  float f1t = f1tok[m * CNH + k];
  float f2t = f2tok[m * CNH + k];

  // ---- layer-1 rows 1..127: rank-1 correction of precomputed (U, wS)
  for (int i = 1; i < CN; ++i) {
    float t0 = 0.f;
    if (adj[adjb + i * CN]) t0 = expf(leakyf(f1int[k * 128 + i - 1] + f2t));
    float den = wS[(b * 4 + k) * 128 + i] + t0;
    float val = (U[((b * 4 + k) * 128 + i) * CGH + c] + t0 * ht) / den;
    x1[i][tid] = __float2bfloat16(eluf(val));
  }

  // ---- layer-1 row 0 (full, per token)
  {
    int j1 = c, j2 = c + 64;
    float e1 = leakyf(f1t + (j1 == 0 ? f2t : f2int[k * 128 + j1 - 1]));
    float wj1 = adj[adjb + j1] ? expf(e1) : 0.f;
    float e2 = leakyf(f1t + f2int[k * 128 + j2 - 1]);
    float wj2 = adj[adjb + j2] ? expf(e2) : 0.f;
    w0[k][j1] = wj1;
    w0[k][j2] = wj2;
    float den0 = wredf(wj1 + wj2);          // all lanes hold row sum
    float acc = w0[k][0] * ht;              // in-wave LDS RAW: safe
    for (int j = 1; j < CN; ++j) acc += w0[k][j] * hint[(k * 128 + j - 1) * CGH + c];
    x1[0][tid] = __float2bfloat16(eluf(acc / den0));
  }
  __syncthreads();

  // ---- layer-2 attention scalars: f2_2[j] = x1[j,:] . (Wo@ao2); f1_2 = x1[0,:] . (Wo@ao1)
  {
    float wa0 = woao2[c], wa1 = woao2[64 + c], wa2 = woao2[128 + c], wa3 = woao2[192 + c];
    for (int j = k; j < CN; j += 4) {
      float p = __bfloat162float(x1[j][c]) * wa0
              + __bfloat162float(x1[j][64 + c]) * wa1
              + __bfloat162float(x1[j][128 + c]) * wa2
              + __bfloat162float(x1[j][192 + c]) * wa3;
      p = wredf(p);
      if (c == 0) f22[j] = p;
    }
    if (k == 0) {
      float p = __bfloat162float(x1[0][c]) * woao1[c]
              + __bfloat162float(x1[0][64 + c]) * woao1[64 + c]
              + __bfloat162float(x1[0][128 + c]) * woao1[128 + c]
              + __bfloat162float(x1[0][192 + c]) * woao1[192 + c];
      p = wredf(p);
      if (c == 0) f12s = p;
    }
  }
  __syncthreads();

  // ---- att2 row 0
  if (tid < CN) {
    float e = leakyf(f12s + f22[tid]);
    w2[tid] = adj[adjb + tid] ? expf(e) : 0.f;
  }
  __syncthreads();
  if (k == 0) {
    float v = wredf(w2[c] + w2[c + 64]);
    if (c == 0) den2s = v;
  }
  // y[col] = sum_j w2[j] * x1[j][col]   (undivided)
  float yacc = 0.f;
  for (int j = 0; j < CN; ++j) yacc += w2[j] * __bfloat162float(x1[j][tid]);
  ybuf[tid] = yacc;
  __syncthreads();

  // hp2[col] = (y @ Wo)[col] / den2 ; g = elu(hp2) + lo[m]
  float hacc = 0.f;
  #pragma unroll 4
  for (int kk = 0; kk < CH; ++kk) hacc += ybuf[kk] * Wo[kk * CH + tid];
  float g = eluf(hacc / den2s) + lo[m * CH + tid];
  gbuf[tid] = g;
  __syncthreads();

  // logits
  if (tid < CV) {
    float acc = bl[tid];
    #pragma unroll 4
    for (int cc = 0; cc < CH; ++cc) acc += gbuf[cc] * Wl[cc * CV + tid];
    out[m * CV + tid] = (s < seq_lens[b]) ? acc : 0.f;
  }
}

}  // namespace

extern "C" void kernel_launch(void* const* d_in, const int* in_sizes, int n_in,
                              void* d_out, int out_size, void* d_ws, size_t ws_size,
                              hipStream_t stream) {
  const float* hidden   = (const float*)d_in[0];
  const int*   seq_lens = (const int*)d_in[1];
  const int*   forced   = (const int*)d_in[2];
  const int*   adj      = (const int*)d_in[3];
  const float* intent   = (const float*)d_in[4];
  const float* emb      = (const float*)d_in[5];
  const float* initt    = (const float*)d_in[6];
  const float* W_ih     = (const float*)d_in[7];
  const float* W_hh     = (const float*)d_in[8];
  const float* b_ih     = (const float*)d_in[9];
  const float* b_hh     = (const float*)d_in[10];
  const float* Wh       = (const float*)d_in[11];
  const float* ah       = (const float*)d_in[12];
  const float* Wo       = (const float*)d_in[13];
  const float* ao       = (const float*)d_in[14];
  const float* Wl       = (const float*)d_in[15];
  const float* bl       = (const float*)d_in[16];
  float* out = (float*)d_out;

  float* ws    = (float*)d_ws;
  float* x     = ws;                       // 2048*384
  float* WpF   = x + CM * CDX;             // 96*1024 f16x2 slots
  float* WtF   = WpF + QREG * CG;          // 1024*32 f16x2 slots
  float* xg    = WtF + CG * QTL;           // 2048*1024
  float* lo    = xg + CM * CG;             // 2048*256
  float* htok  = lo + CM * CH;             // 2048*256
  float* f1tok = htok + CM * CH;           // 2048*4
  float* f2tok = f1tok + CM * CNH;         // 2048*4
  float* hint  = f2tok + CM * CNH;         // 4*128*64
  float* f1int = hint + CNH * 128 * CGH;   // 4*128
  float* f2int = f1int + CNH * 128;        // 4*128
  float* U     = f2int + CNH * 128;        // 32*4*128*64
  float* wS    = U + CB * CNH * 128 * CGH; // 32*4*128
  float* woao1 = wS + CB * CNH * 128;      // 256
  float* woao2 = woao1 + CH;               // 256
  f16x2* Wp    = (f16x2*)WpF;
  f16x2* Wt    = (f16x2*)WtF;

  k_build_x<<<(CM * CDX + 255) / 256, 256, 0, stream>>>(hidden, forced, emb, initt, x);
  k_whh_pack<<<CG / 64, 256, 0, stream>>>(W_hh, Wp, Wt);
  k_hint<<<CNH * 127, 64, 0, stream>>>(intent, Wh, ah, hint, f1int, f2int);
  k_woao<<<1, 512, 0, stream>>>(Wo, ao, woao1, woao2);
  k_xg2<<<CM / 8, 256, 0, stream>>>(x, W_ih, b_ih, b_hh, xg);
  k_U<<<CB * CNH, 256, 0, stream>>>(hint, f1int, f2int, adj, U, wS);
  k_lstm3<<<CB, 512, 0, stream>>>(xg, Wp, Wt, lo);
  k_htok<<<CM / 8, 256, 0, stream>>>(lo, Wh, ah, htok, f1tok, f2tok);
  k_perm<<<CM, 256, 0, stream>>>(lo, htok, f1tok, f2tok, hint, f1int, f2int,
                                 U, wS, woao1, woao2, adj, Wo, Wl, bl, seq_lens, out);
}

// Round 4
// 681.736 us; speedup vs baseline: 2.4768x; 1.5443x over previous
//
#include <hip/hip_runtime.h>
#include <hip/hip_bf16.h>

namespace {

constexpr int CB   = 32;            // batch
constexpr int CS   = 64;            // seq len
constexpr int CDIN = 256;           // encoder hidden
constexpr int CH   = 256;           // LSTM hidden / GAT feature
constexpr int CE   = 128;           // embedding dim
constexpr int CV   = 128;           // vocab
constexpr int CGH  = 64;            // per-head GAT dim
constexpr int CNH  = 4;             // heads
constexpr int CN   = 128;           // graph nodes (1 token + 127 intents)
constexpr int CDX  = CDIN + CE;     // 384 LSTM input
constexpr int CG   = 4 * CH;        // 1024 gates
constexpr int CM   = CB * CS;       // 2048 tokens
constexpr int QREG = 96;            // weight half2-pairs kept in VGPRs per gate
constexpr int QTL  = 128 - QREG;    // 32 streamed pairs per gate

typedef _Float16 f16x2 __attribute__((ext_vector_type(2)));
typedef _Float16 f16x8 __attribute__((ext_vector_type(8)));
typedef float    f32x4 __attribute__((ext_vector_type(4)));

__device__ __forceinline__ float leakyf(float x) { return x >= 0.f ? x : 0.2f * x; }
__device__ __forceinline__ float eluf(float x)   { return x > 0.f ? x : expm1f(x); }
__device__ __forceinline__ float sigmf(float x)  { return 1.f / (1.f + expf(-x)); }
__device__ __forceinline__ float wredf(float v) {
  #pragma unroll
  for (int off = 32; off; off >>= 1) v += __shfl_xor(v, off);
  return v;
}

// x[m, 0:256] = hidden[b,s,:]; x[m, 256:384] = (s==0 ? init : embedding[forced[b,s-1]])
__global__ void k_build_x(const float* __restrict__ hidden, const int* __restrict__ forced,
                          const float* __restrict__ emb, const float* __restrict__ initt,
                          float* __restrict__ x) {
  int idx = blockIdx.x * 256 + threadIdx.x;
  if (idx >= CM * CDX) return;
  int m = idx / CDX, d = idx - m * CDX;
  float v;
  if (d < CDIN) {
    v = hidden[m * CDIN + d];
  } else {
    int e = d - CDIN;
    v = (m % CS == 0) ? initt[e] : emb[forced[m - 1] * CE + e];
  }
  x[idx] = v;
}

// Pack W_hh [1024 g][256 k] fp32 -> Wp[q][g] (q<96, gate-minor for coalesced reg fill)
// and Wt[g][j] (j=q-96, gate-major so each thread's tail is contiguous f16x8 chunks).
__global__ void k_whh_pack(const float* __restrict__ Whh, f16x2* __restrict__ Wp,
                           f16x2* __restrict__ Wt) {
  __shared__ float tile[64][257];
  int g0 = blockIdx.x * 64;
  for (int idx = threadIdx.x; idx < 64 * 256; idx += 256) {
    int gl = idx >> 8, kk = idx & 255;
    tile[gl][kk] = Whh[(g0 + gl) * CH + kk];
  }
  __syncthreads();
  for (int idx = threadIdx.x; idx < 128 * 64; idx += 256) {
    int q = idx >> 6, gl = idx & 63;
    f16x2 w = { (_Float16)tile[gl][2 * q], (_Float16)tile[gl][2 * q + 1] };
    if (q < QREG) Wp[q * CG + g0 + gl] = w;
    else          Wt[(g0 + gl) * QTL + (q - QREG)] = w;
  }
}

// hint[k][i][c] = intent[i] . Wh[k][:,c];  f1int/f2int[k][i] = hint . ah[k][0:64 / 64:128]
__global__ void k_hint(const float* __restrict__ intent, const float* __restrict__ Wh,
                       const float* __restrict__ ah, float* __restrict__ hint,
                       float* __restrict__ f1int, float* __restrict__ f2int) {
  int k = blockIdx.x / 127;
  int i = blockIdx.x % 127;
  int c = threadIdx.x;  // 64 threads
  float acc = 0.f;
  for (int d = 0; d < CH; ++d)
    acc += intent[i * CH + d] * Wh[(k * CH + d) * CGH + c];
  hint[(k * 128 + i) * CGH + c] = acc;
  float r1 = wredf(acc * ah[k * 128 + c]);
  float r2 = wredf(acc * ah[k * 128 + 64 + c]);
  if (c == 0) { f1int[k * 128 + i] = r1; f2int[k * 128 + i] = r2; }
}

// woao1[kk] = Wo[kk,:] . ao[0:256];  woao2[kk] = Wo[kk,:] . ao[256:512]
__global__ void k_woao(const float* __restrict__ Wo, const float* __restrict__ ao,
                       float* __restrict__ woao1, float* __restrict__ woao2) {
  int t = threadIdx.x;  // 512 threads
  if (t < CH) {
    float acc = 0.f;
    for (int c = 0; c < CH; ++c) acc += Wo[t * CH + c] * ao[c];
    woao1[t] = acc;
  } else {
    int tt = t - CH;
    float acc = 0.f;
    for (int c = 0; c < CH; ++c) acc += Wo[tt * CH + c] * ao[CH + c];
    woao2[tt] = acc;
  }
}

// xg[m,g] = x[m,:] . W_ih[g,:] + b_ih[g] + b_hh[g]
// 256 blocks (8 m each), 256 threads (4 gates each), float4 everywhere.
__global__ void k_xg2(const float* __restrict__ x, const float* __restrict__ Wih,
                      const float* __restrict__ bih, const float* __restrict__ bhh,
                      float* __restrict__ xg) {
  __shared__ f32x4 xs[8][CDX / 4];  // 12 KB
  int m0 = blockIdx.x * 8;
  int tid = threadIdx.x;
  for (int idx = tid; idx < 8 * (CDX / 4); idx += 256) {
    int r = idx / (CDX / 4), q = idx - r * (CDX / 4);
    xs[r][q] = ((const f32x4*)x)[(m0 + r) * (CDX / 4) + q];
  }
  __syncthreads();
  int g0 = tid * 4;
  float acc[8][4];
  #pragma unroll
  for (int r = 0; r < 8; ++r)
    #pragma unroll
    for (int j = 0; j < 4; ++j) acc[r][j] = 0.f;
  const f32x4* w0 = (const f32x4*)(Wih + (g0 + 0) * CDX);
  const f32x4* w1 = (const f32x4*)(Wih + (g0 + 1) * CDX);
  const f32x4* w2 = (const f32x4*)(Wih + (g0 + 2) * CDX);
  const f32x4* w3 = (const f32x4*)(Wih + (g0 + 3) * CDX);
  #pragma unroll 2
  for (int q = 0; q < CDX / 4; ++q) {
    f32x4 wa = w0[q], wb = w1[q], wc = w2[q], wd = w3[q];
    #pragma unroll
    for (int r = 0; r < 8; ++r) {
      f32x4 xv = xs[r][q];
      acc[r][0] += wa.x * xv.x + wa.y * xv.y + wa.z * xv.z + wa.w * xv.w;
      acc[r][1] += wb.x * xv.x + wb.y * xv.y + wb.z * xv.z + wb.w * xv.w;
      acc[r][2] += wc.x * xv.x + wc.y * xv.y + wc.z * xv.z + wc.w * xv.w;
      acc[r][3] += wd.x * xv.x + wd.y * xv.y + wd.z * xv.z + wd.w * xv.w;
    }
  }
  f32x4 bias = { bih[g0] + bhh[g0], bih[g0 + 1] + bhh[g0 + 1],
                 bih[g0 + 2] + bhh[g0 + 2], bih[g0 + 3] + bhh[g0 + 3] };
  #pragma unroll
  for (int r = 0; r < 8; ++r) {
    f32x4 st = { acc[r][0] + bias.x, acc[r][1] + bias.y,
                 acc[r][2] + bias.z, acc[r][3] + bias.w };
    ((f32x4*)xg)[((m0 + r) * CG + g0) / 4] = st;
  }
}

// One block per batch element; 512 threads, 2 gates each (g and g+512).
__global__ __launch_bounds__(512, 1) void k_lstm3(const float* __restrict__ xg,
                                                  const f16x2* __restrict__ Wp,
                                                  const f16x2* __restrict__ Wt,
                                                  float* __restrict__ lo) {
  int b = blockIdx.x;
  int tt = threadIdx.x;
  int g0 = tt, g1 = tt + 512;
  __shared__ float gbuf[CG];
  __shared__ f16x8 hsh8[CH / 8];    // 256 h as fp16, 16B-aligned
  _Float16* hsh = (_Float16*)hsh8;

  f16x2 w0[QREG], w1[QREG];
  #pragma unroll
  for (int q = 0; q < QREG; ++q) {
    w0[q] = Wp[q * CG + g0];
    w1[q] = Wp[q * CG + g1];
  }
  const f16x8* wt0 = (const f16x8*)(Wt + g0 * QTL);  // 8 chunks of 4 pairs
  const f16x8* wt1 = (const f16x8*)(Wt + g1 * QTL);

  if (tt < CH) hsh[tt] = (_Float16)0.f;
  float c = 0.f;
  __syncthreads();

  const float* xgb = xg + b * CS * CG;
  float nx0 = xgb[g0], nx1 = xgb[g1];
  for (int t = 0; t < CS; ++t) {
    asm volatile("" ::: "memory");   // keep tail-weight loads inside the loop
    float acc0 = nx0, acc1 = nx1;
    int tn = (t + 1 < CS) ? t + 1 : t;
    nx0 = xgb[tn * CG + g0];
    nx1 = xgb[tn * CG + g1];
    #pragma unroll
    for (int jc = 0; jc < QREG / 4; ++jc) {
      f16x8 hv = hsh8[jc];
      f16x2 ha = __builtin_shufflevector(hv, hv, 0, 1);
      f16x2 hb = __builtin_shufflevector(hv, hv, 2, 3);
      f16x2 hc = __builtin_shufflevector(hv, hv, 4, 5);
      f16x2 hd = __builtin_shufflevector(hv, hv, 6, 7);
      acc0 = __builtin_amdgcn_fdot2(w0[4 * jc + 0], ha, acc0, false);
      acc0 = __builtin_amdgcn_fdot2(w0[4 * jc + 1], hb, acc0, false);
      acc0 = __builtin_amdgcn_fdot2(w0[4 * jc + 2], hc, acc0, false);
      acc0 = __builtin_amdgcn_fdot2(w0[4 * jc + 3], hd, acc0, false);
      acc1 = __builtin_amdgcn_fdot2(w1[4 * jc + 0], ha, acc1, false);
      acc1 = __builtin_amdgcn_fdot2(w1[4 * jc + 1], hb, acc1, false);
      acc1 = __builtin_amdgcn_fdot2(w1[4 * jc + 2], hc, acc1, false);
      acc1 = __builtin_amdgcn_fdot2(w1[4 * jc + 3], hd, acc1, false);
    }
    #pragma unroll
    for (int jc = 0; jc < QTL / 4; ++jc) {
      f16x8 hv = hsh8[QREG / 4 + jc];
      f16x8 wa = wt0[jc];
      f16x8 wb = wt1[jc];
      f16x2 ha = __builtin_shufflevector(hv, hv, 0, 1);
      f16x2 hb = __builtin_shufflevector(hv, hv, 2, 3);
      f16x2 hc = __builtin_shufflevector(hv, hv, 4, 5);
      f16x2 hd = __builtin_shufflevector(hv, hv, 6, 7);
      acc0 = __builtin_amdgcn_fdot2(__builtin_shufflevector(wa, wa, 0, 1), ha, acc0, false);
      acc0 = __builtin_amdgcn_fdot2(__builtin_shufflevector(wa, wa, 2, 3), hb, acc0, false);
      acc0 = __builtin_amdgcn_fdot2(__builtin_shufflevector(wa, wa, 4, 5), hc, acc0, false);
      acc0 = __builtin_amdgcn_fdot2(__builtin_shufflevector(wa, wa, 6, 7), hd, acc0, false);
      acc1 = __builtin_amdgcn_fdot2(__builtin_shufflevector(wb, wb, 0, 1), ha, acc1, false);
      acc1 = __builtin_amdgcn_fdot2(__builtin_shufflevector(wb, wb, 2, 3), hb, acc1, false);
      acc1 = __builtin_amdgcn_fdot2(__builtin_shufflevector(wb, wb, 4, 5), hc, acc1, false);
      acc1 = __builtin_amdgcn_fdot2(__builtin_shufflevector(wb, wb, 6, 7), hd, acc1, false);
    }
    gbuf[g0] = acc0;
    gbuf[g1] = acc1;
    __syncthreads();
    if (tt < CH) {
      float gi = gbuf[tt], gf = gbuf[CH + tt], gg = gbuf[2 * CH + tt], go = gbuf[3 * CH + tt];
      c = sigmf(gf) * c + sigmf(gi) * tanhf(gg);
      float h = sigmf(go) * tanhf(c);
      hsh[tt] = (_Float16)h;
      lo[(b * CS + t) * CH + tt] = h;
    }
    __syncthreads();
  }
}

// per (b,head): wS[i] = sum_{j>=1,adj} w_ij ; U[i][c] = sum_j w_ij * hint[j][c]   (rows i=1..127)
__global__ void k_U(const float* __restrict__ hint, const float* __restrict__ f1int,
                    const float* __restrict__ f2int, const int* __restrict__ adj,
                    float* __restrict__ U, float* __restrict__ wS) {
  int b = blockIdx.x >> 2, k = blockIdx.x & 3;
  int grp = threadIdx.x >> 6, c = threadIdx.x & 63;
  __shared__ float wbuf[4][128];
  const int adjb = b * CN * CN;
  for (int i = 1 + grp; i < 128; i += 4) {
    float f1 = f1int[k * 128 + (i - 1)];
    int j1 = 1 + c, j2 = 65 + c;
    float w1 = 0.f, w2 = 0.f;
    if (adj[adjb + i * CN + j1]) w1 = expf(leakyf(f1 + f2int[k * 128 + j1 - 1]));
    if (j2 < 128 && adj[adjb + i * CN + j2]) w2 = expf(leakyf(f1 + f2int[k * 128 + j2 - 1]));
    wbuf[grp][c] = w1;
    wbuf[grp][64 + c] = w2;              // slot 127 (c=63) = 0
    float rs = wredf(w1 + w2);
    float acc = 0.f;
    for (int jj = 0; jj < 127; ++jj)     // jj = j-1
      acc += wbuf[grp][jj] * hint[(k * 128 + jj) * CGH + c];
    if (c == 0) wS[(b * 4 + k) * 128 + i] = rs;
    U[((b * 4 + k) * 128 + i) * CGH + c] = acc;
  }
}

// htok[m, k*64+c] = lo[m,:] . Wh[k][:,c];  f1tok/f2tok[m,k] reductions
__global__ void k_htok(const float* __restrict__ lo, const float* __restrict__ Wh,
                       const float* __restrict__ ah, float* __restrict__ htok,
                       float* __restrict__ f1tok, float* __restrict__ f2tok) {
  __shared__ float ls[8][CH];
  int m0 = blockIdx.x * 8;
  int tid = threadIdx.x;
  int k = tid >> 6, c = tid & 63;
  for (int idx = tid; idx < 8 * CH; idx += 256) {
    int r = idx >> 8, d = idx & 255;
    ls[r][d] = lo[(m0 + r) * CH + d];
  }
  __syncthreads();
  float acc[8];
  #pragma unroll
  for (int r = 0; r < 8; ++r) acc[r] = 0.f;
  #pragma unroll 4
  for (int d = 0; d < CH; ++d) {
    float w = Wh[(k * CH + d) * CGH + c];
    #pragma unroll
    for (int r = 0; r < 8; ++r) acc[r] += w * ls[r][d];
  }
  float a1 = ah[k * 128 + c], a2 = ah[k * 128 + 64 + c];
  #pragma unroll
  for (int r = 0; r < 8; ++r) {
    htok[(m0 + r) * CH + tid] = acc[r];
    float r1 = wredf(acc[r] * a1);
    float r2 = wredf(acc[r] * a2);
    if (c == 0) { f1tok[(m0 + r) * CNH + k] = r1; f2tok[(m0 + r) * CNH + k] = r2; }
  }
}

// Per-token fused GAT layer-2 + logits, two-pass (no x1 LDS tile), adjacency-pruned.
// One block per token m, 256 threads (wave k = head, lane c).
__global__ __launch_bounds__(256) void k_perm2(
    const float* __restrict__ lo, const float* __restrict__ htok,
    const float* __restrict__ f1tok, const float* __restrict__ f2tok,
    const float* __restrict__ hint, const float* __restrict__ f1int,
    const float* __restrict__ f2int, const float* __restrict__ U,
    const float* __restrict__ wS, const float* __restrict__ woao1,
    const float* __restrict__ woao2, const int* __restrict__ adj,
    const float* __restrict__ Wo, const float* __restrict__ Wl,
    const float* __restrict__ bl, const int* __restrict__ seq_lens,
    float* __restrict__ out) {
  int m = blockIdx.x;
  int b = m >> 6, s = m & 63;
  int tid = threadIdx.x;
  int k = tid >> 6, c = tid & 63;

  __shared__ float ht[CH];        // htok row for this token
  __shared__ float s1[CNH][CN];   // rden per (head, row)
  __shared__ float s2[CNH][CN];   // t0*rden per (head, row)
  __shared__ float w0[CNH][CN];   // layer-1 row-0 attention weights
  __shared__ float x10[CH];       // layer-1 row 0 (f32)
  __shared__ float f22[CN];       // layer-2 f2 per list slot
  __shared__ float w2s[CN];       // layer-2 att weight per list slot
  __shared__ float ybuf[CH];
  __shared__ float gbuf[CH];
  __shared__ float part[2][CV];
  __shared__ int   list[CN];
  __shared__ int   cnt;
  __shared__ float f12s, f220s, den2s;

  const int adjb = b * CN * CN;
  ht[tid] = htok[m * CH + tid];
  float f1t = f1tok[m * CNH + k];
  float f2t = f2tok[m * CNH + k];

  // ---- adjacency list of row 0 (j>=1), deterministic ballot compaction (wave 0)
  if (k == 0) {
    int j1 = 1 + c;            // 1..64
    int j2 = 65 + c;           // 65..127 valid for c<63
    bool fl1 = adj[adjb + j1] != 0;
    bool fl2 = (j2 < CN) && (adj[adjb + j2] != 0);
    unsigned long long b1 = __ballot(fl1);
    unsigned long long b2 = __ballot(fl2);
    unsigned long long below = (1ull << c) - 1ull;
    int n1 = __popcll(b1);
    if (fl1) list[__popcll(b1 & below)] = j1;
    if (fl2) list[n1 + __popcll(b2 & below)] = j2;
    if (c == 0) cnt = n1 + __popcll(b2);
  }

  // ---- per (head,row) scalars: s1 = 1/den, s2 = t0/den   (rows 1..127)
  for (int idx = tid; idx < CNH * CN; idx += 256) {
    int k2 = idx >> 7, i = idx & 127;
    if (i == 0) continue;
    float t0 = 0.f;
    if (adj[adjb + i * CN]) t0 = expf(leakyf(f1int[k2 * 128 + i - 1] + f2tok[m * CNH + k2]));
    float rd = 1.f / (wS[(b * 4 + k2) * 128 + i] + t0);
    s1[k2][i] = rd;
    s2[k2][i] = t0 * rd;
  }

  // ---- layer-1 row 0 attention weights (own head)
  float den0;
  {
    int j1 = c, j2 = c + 64;
    float e1 = leakyf(f1t + (j1 == 0 ? f2t : f2int[k * 128 + j1 - 1]));
    float wj1 = adj[adjb + j1] ? expf(e1) : 0.f;
    float e2 = leakyf(f1t + f2int[k * 128 + j2 - 1]);
    float wj2 = adj[adjb + j2] ? expf(e2) : 0.f;
    w0[k][j1] = wj1;
    w0[k][j2] = wj2;
    den0 = wredf(wj1 + wj2);
  }
  __syncthreads();   // list, cnt, s1, s2, w0, ht ready
  const int na = cnt;

  // ---- layer-1 row 0 (pruned dot over adjacent j)
  {
    float acc = w0[k][0] * ht[tid];
    #pragma unroll 4
    for (int l = 0; l < na; ++l) {
      int j = list[l];
      acc += w0[k][j] * hint[(k * 128 + j - 1) * CGH + c];
    }
    x10[tid] = eluf(acc / den0);
  }
  __syncthreads();   // x10 ready

  // ---- layer-2 attention scalars
  if (k == 0) {      // f1_2 = x1[0] . woao1
    float p = x10[c] * woao1[c] + x10[c + 64] * woao1[c + 64]
            + x10[c + 128] * woao1[c + 128] + x10[c + 192] * woao1[c + 192];
    p = wredf(p);
    if (c == 0) f12s = p;
  }
  if (k == 1) {      // f2_2[0] = x1[0] . woao2
    float p = x10[c] * woao2[c] + x10[c + 64] * woao2[c + 64]
            + x10[c + 128] * woao2[c + 128] + x10[c + 192] * woao2[c + 192];
    p = wredf(p);
    if (c == 0) f220s = p;
  }
  // f2_2[j] for adjacent j (pass 1 of x1 recompute): wave k handles slots l%4==k
  for (int l = k; l < na; l += 4) {
    int j = list[l];
    float p = 0.f;
    #pragma unroll
    for (int kk = 0; kk < 4; ++kk) {
      float u = U[((b * 4 + kk) * 128 + j) * CGH + c];
      float val = eluf(u * s1[kk][j] + s2[kk][j] * ht[kk * 64 + c]);
      p += val * woao2[kk * 64 + c];
    }
    p = wredf(p);
    if (c == 0) f22[l] = p;
  }
  __syncthreads();   // f12s, f220s, f22 ready

  float w20 = expf(leakyf(f12s + f220s));   // j=0 self-loop always adjacent
  if (tid < na) w2s[tid] = expf(leakyf(f12s + f22[tid]));
  __syncthreads();   // w2s ready
  if (k == 0) {
    float v = (c < na ? w2s[c] : 0.f) + (c + 64 < na ? w2s[c + 64] : 0.f);
    v = wredf(v);
    if (c == 0) den2s = v + w20;
  }

  // ---- y[col] = sum_j w2[j] * x1[j][col]  (pass 2 of x1 recompute, own head cols)
  {
    float yacc = w20 * x10[tid];
    #pragma unroll 4
    for (int l = 0; l < na; ++l) {
      int j = list[l];
      float u = U[((b * 4 + k) * 128 + j) * CGH + c];
      float val = eluf(u * s1[k][j] + s2[k][j] * ht[tid]);
      yacc += w2s[l] * val;
    }
    ybuf[tid] = yacc;
  }
  __syncthreads();   // ybuf, den2s ready

  // ---- hp2 = (y @ Wo)/den2 ; g = elu(hp2) + lo[m]
  float hacc = 0.f;
  #pragma unroll 8
  for (int kk = 0; kk < CH; ++kk) hacc += ybuf[kk] * Wo[kk * CH + tid];
  float g = eluf(hacc / den2s) + lo[m * CH + tid];
  gbuf[tid] = g;
  __syncthreads();

  // ---- logits, split across two halves of the contraction
  {
    int col = tid & 127, hh = tid >> 7;
    float acc = 0.f;
    #pragma unroll 8
    for (int cc = hh * 128; cc < hh * 128 + 128; ++cc) acc += gbuf[cc] * Wl[cc * CV + col];
    part[hh][col] = acc;
  }
  __syncthreads();
  if (tid < CV) {
    float r = part[0][tid] + part[1][tid] + bl[tid];
    out[m * CV + tid] = (s < seq_lens[b]) ? r : 0.f;
  }
}

}  // namespace

extern "C" void kernel_launch(void* const* d_in, const int* in_sizes, int n_in,
                              void* d_out, int out_size, void* d_ws, size_t ws_size,
                              hipStream_t stream) {
  const float* hidden   = (const float*)d_in[0];
  const int*   seq_lens = (const int*)d_in[1];
  const int*   forced   = (const int*)d_in[2];
  const int*   adj      = (const int*)d_in[3];
  const float* intent   = (const float*)d_in[4];
  const float* emb      = (const float*)d_in[5];
  const float* initt    = (const float*)d_in[6];
  const float* W_ih     = (const float*)d_in[7];
  const float* W_hh     = (const float*)d_in[8];
  const float* b_ih     = (const float*)d_in[9];
  const float* b_hh     = (const float*)d_in[10];
  const float* Wh       = (const float*)d_in[11];
  const float* ah       = (const float*)d_in[12];
  const float* Wo       = (const float*)d_in[13];
  const float* ao       = (const float*)d_in[14];
  const float* Wl       = (const float*)d_in[15];
  const float* bl       = (const float*)d_in[16];
  float* out = (float*)d_out;

  float* ws    = (float*)d_ws;
  float* x     = ws;                       // 2048*384
  float* WpF   = x + CM * CDX;             // 96*1024 f16x2 slots
  float* WtF   = WpF + QREG * CG;          // 1024*32 f16x2 slots
  float* xg    = WtF + CG * QTL;           // 2048*1024
  float* lo    = xg + CM * CG;             // 2048*256
  float* htok  = lo + CM * CH;             // 2048*256
  float* f1tok = htok + CM * CH;           // 2048*4
  float* f2tok = f1tok + CM * CNH;         // 2048*4
  float* hint  = f2tok + CM * CNH;         // 4*128*64
  float* f1int = hint + CNH * 128 * CGH;   // 4*128
  float* f2int = f1int + CNH * 128;        // 4*128
  float* U     = f2int + CNH * 128;        // 32*4*128*64
  float* wS    = U + CB * CNH * 128 * CGH; // 32*4*128
  float* woao1 = wS + CB * CNH * 128;      // 256
  float* woao2 = woao1 + CH;               // 256
  f16x2* Wp    = (f16x2*)WpF;
  f16x2* Wt    = (f16x2*)WtF;

  k_build_x<<<(CM * CDX + 255) / 256, 256, 0, stream>>>(hidden, forced, emb, initt, x);
  k_whh_pack<<<CG / 64, 256, 0, stream>>>(W_hh, Wp, Wt);
  k_hint<<<CNH * 127, 64, 0, stream>>>(intent, Wh, ah, hint, f1int, f2int);
  k_woao<<<1, 512, 0, stream>>>(Wo, ao, woao1, woao2);
  k_xg2<<<CM / 8, 256, 0, stream>>>(x, W_ih, b_ih, b_hh, xg);
  k_U<<<CB * CNH, 256, 0, stream>>>(hint, f1int, f2int, adj, U, wS);
  k_lstm3<<<CB, 512, 0, stream>>>(xg, Wp, Wt, lo);
  k_htok<<<CM / 8, 256, 0, stream>>>(lo, Wh, ah, htok, f1tok, f2tok);
  k_perm2<<<CM, 256, 0, stream>>>(lo, htok, f1tok, f2tok, hint, f1int, f2int,
                                  U, wS, woao1, woao2, adj, Wo, Wl, bl, seq_lens, out);
}

// Round 5
// 660.254 us; speedup vs baseline: 2.5574x; 1.0325x over previous
//
#include <hip/hip_runtime.h>
#include <hip/hip_bf16.h>

namespace {

constexpr int CB   = 32;            // batch
constexpr int CS   = 64;            // seq len
constexpr int CDIN = 256;           // encoder hidden
constexpr int CH   = 256;           // LSTM hidden / GAT feature
constexpr int CE   = 128;           // embedding dim
constexpr int CV   = 128;           // vocab
constexpr int CGH  = 64;            // per-head GAT dim
constexpr int CNH  = 4;             // heads
constexpr int CN   = 128;           // graph nodes (1 token + 127 intents)
constexpr int CDX  = CDIN + CE;     // 384 LSTM input
constexpr int CG   = 4 * CH;        // 1024 gates
constexpr int CM   = CB * CS;       // 2048 tokens
constexpr int QREG = 80;            // weight half2-pairs kept in VGPRs per gate
constexpr int QTL  = 128 - QREG;    // 48 streamed pairs per gate

typedef _Float16 f16x2 __attribute__((ext_vector_type(2)));
typedef _Float16 f16x8 __attribute__((ext_vector_type(8)));
typedef float    f32x4 __attribute__((ext_vector_type(4)));

__device__ __forceinline__ float leakyf(float x) { return x >= 0.f ? x : 0.2f * x; }
__device__ __forceinline__ float eluf(float x)   { return x > 0.f ? x : expm1f(x); }
__device__ __forceinline__ float sigmf(float x)  { return 1.f / (1.f + expf(-x)); }
__device__ __forceinline__ float wredf(float v) {
  #pragma unroll
  for (int off = 32; off; off >>= 1) v += __shfl_xor(v, off);
  return v;
}

// x[m, 0:256] = hidden[b,s,:]; x[m, 256:384] = (s==0 ? init : embedding[forced[b,s-1]])
__global__ void k_build_x(const float* __restrict__ hidden, const int* __restrict__ forced,
                          const float* __restrict__ emb, const float* __restrict__ initt,
                          float* __restrict__ x) {
  int idx = blockIdx.x * 256 + threadIdx.x;
  if (idx >= CM * CDX) return;
  int m = idx / CDX, d = idx - m * CDX;
  float v;
  if (d < CDIN) {
    v = hidden[m * CDIN + d];
  } else {
    int e = d - CDIN;
    v = (m % CS == 0) ? initt[e] : emb[forced[m - 1] * CE + e];
  }
  x[idx] = v;
}

// Pack W_hh [1024 g][256 k] fp32 -> Wp[q][g] (q<QREG, gate-minor for coalesced reg fill)
// and Wt[g][j] (j=q-QREG, gate-major so each thread's tail is contiguous f16x8 chunks).
__global__ void k_whh_pack(const float* __restrict__ Whh, f16x2* __restrict__ Wp,
                           f16x2* __restrict__ Wt) {
  __shared__ float tile[64][257];
  int g0 = blockIdx.x * 64;
  for (int idx = threadIdx.x; idx < 64 * 256; idx += 256) {
    int gl = idx >> 8, kk = idx & 255;
    tile[gl][kk] = Whh[(g0 + gl) * CH + kk];
  }
  __syncthreads();
  for (int idx = threadIdx.x; idx < 128 * 64; idx += 256) {
    int q = idx >> 6, gl = idx & 63;
    f16x2 w = { (_Float16)tile[gl][2 * q], (_Float16)tile[gl][2 * q + 1] };
    if (q < QREG) Wp[q * CG + g0 + gl] = w;
    else          Wt[(g0 + gl) * QTL + (q - QREG)] = w;
  }
}

// hint[k][i][c] = intent[i] . Wh[k][:,c];  f1int/f2int[k][i] = hint . ah[k][0:64 / 64:128]
__global__ void k_hint(const float* __restrict__ intent, const float* __restrict__ Wh,
                       const float* __restrict__ ah, float* __restrict__ hint,
                       float* __restrict__ f1int, float* __restrict__ f2int) {
  int k = blockIdx.x / 127;
  int i = blockIdx.x % 127;
  int c = threadIdx.x;  // 64 threads
  float acc = 0.f;
  for (int d = 0; d < CH; ++d)
    acc += intent[i * CH + d] * Wh[(k * CH + d) * CGH + c];
  hint[(k * 128 + i) * CGH + c] = acc;
  float r1 = wredf(acc * ah[k * 128 + c]);
  float r2 = wredf(acc * ah[k * 128 + 64 + c]);
  if (c == 0) { f1int[k * 128 + i] = r1; f2int[k * 128 + i] = r2; }
}

// woao1[kk] = Wo[kk,:] . ao[0:256];  woao2[kk] = Wo[kk,:] . ao[256:512]
__global__ void k_woao(const float* __restrict__ Wo, const float* __restrict__ ao,
                       float* __restrict__ woao1, float* __restrict__ woao2) {
  int t = threadIdx.x;  // 512 threads
  if (t < CH) {
    float acc = 0.f;
    for (int c = 0; c < CH; ++c) acc += Wo[t * CH + c] * ao[c];
    woao1[t] = acc;
  } else {
    int tt = t - CH;
    float acc = 0.f;
    for (int c = 0; c < CH; ++c) acc += Wo[tt * CH + c] * ao[CH + c];
    woao2[tt] = acc;
  }
}

// xg[m,g] = x[m,:] . W_ih[g,:] + b_ih[g] + b_hh[g]
__global__ void k_xg2(const float* __restrict__ x, const float* __restrict__ Wih,
                      const float* __restrict__ bih, const float* __restrict__ bhh,
                      float* __restrict__ xg) {
  __shared__ f32x4 xs[8][CDX / 4];  // 12 KB
  int m0 = blockIdx.x * 8;
  int tid = threadIdx.x;
  for (int idx = tid; idx < 8 * (CDX / 4); idx += 256) {
    int r = idx / (CDX / 4), q = idx - r * (CDX / 4);
    xs[r][q] = ((const f32x4*)x)[(m0 + r) * (CDX / 4) + q];
  }
  __syncthreads();
  int g0 = tid * 4;
  float acc[8][4];
  #pragma unroll
  for (int r = 0; r < 8; ++r)
    #pragma unroll
    for (int j = 0; j < 4; ++j) acc[r][j] = 0.f;
  const f32x4* w0 = (const f32x4*)(Wih + (g0 + 0) * CDX);
  const f32x4* w1 = (const f32x4*)(Wih + (g0 + 1) * CDX);
  const f32x4* w2 = (const f32x4*)(Wih + (g0 + 2) * CDX);
  const f32x4* w3 = (const f32x4*)(Wih + (g0 + 3) * CDX);
  #pragma unroll 2
  for (int q = 0; q < CDX / 4; ++q) {
    f32x4 wa = w0[q], wb = w1[q], wc = w2[q], wd = w3[q];
    #pragma unroll
    for (int r = 0; r < 8; ++r) {
      f32x4 xv = xs[r][q];
      acc[r][0] += wa.x * xv.x + wa.y * xv.y + wa.z * xv.z + wa.w * xv.w;
      acc[r][1] += wb.x * xv.x + wb.y * xv.y + wb.z * xv.z + wb.w * xv.w;
      acc[r][2] += wc.x * xv.x + wc.y * xv.y + wc.z * xv.z + wc.w * xv.w;
      acc[r][3] += wd.x * xv.x + wd.y * xv.y + wd.z * xv.z + wd.w * xv.w;
    }
  }
  f32x4 bias = { bih[g0] + bhh[g0], bih[g0 + 1] + bhh[g0 + 1],
                 bih[g0 + 2] + bhh[g0 + 2], bih[g0 + 3] + bhh[g0 + 3] };
  #pragma unroll
  for (int r = 0; r < 8; ++r) {
    f32x4 st = { acc[r][0] + bias.x, acc[r][1] + bias.y,
                 acc[r][2] + bias.z, acc[r][3] + bias.w };
    ((f32x4*)xg)[((m0 + r) * CG + g0) / 4] = st;
  }
}

// One block per batch element; 512 threads, 2 gates each (g and g+512).
// QREG pairs/gate cached in VGPRs (no memory clobber!); QTL-pair tail streamed
// per step via an opaque pointer (defeats LICM without invalidating reg cache).
__global__ __launch_bounds__(512, 2) void k_lstm4(const float* __restrict__ xg,
                                                  const f16x2* __restrict__ Wp,
                                                  const f16x2* __restrict__ Wt,
                                                  float* __restrict__ lo) {
  int b = blockIdx.x;
  int tt = threadIdx.x;
  int g0 = tt, g1 = tt + 512;
  __shared__ float gbuf[CG];
  __shared__ f16x8 hsh8[CH / 8];    // 256 h as fp16, 16B-aligned
  _Float16* hsh = (_Float16*)hsh8;

  f16x2 w0[QREG], w1[QREG];
  #pragma unroll
  for (int q = 0; q < QREG; ++q) {
    w0[q] = Wp[q * CG + g0];
    w1[q] = Wp[q * CG + g1];
  }
  unsigned long long wt0a = (unsigned long long)(Wt + g0 * QTL);
  unsigned long long wt1a = (unsigned long long)(Wt + g1 * QTL);

  if (tt < CH) hsh[tt] = (_Float16)0.f;
  float c = 0.f;
  __syncthreads();

  const float* xgb = xg + b * CS * CG;
  float nx0 = xgb[g0], nx1 = xgb[g1];
  for (int t = 0; t < CS; ++t) {
    float acc0 = nx0, acc1 = nx1;
    int tn = (t + 1 < CS) ? t + 1 : t;
    nx0 = xgb[tn * CG + g0];
    nx1 = xgb[tn * CG + g1];
    // opaque pointer rotation: loads below can't be hoisted/CSE'd across steps,
    // but w0/w1 register cache is untouched (no memory clobber).
    asm volatile("" : "+v"(wt0a), "+v"(wt1a));
    const f16x8* wt0p = (const f16x8*)wt0a;
    const f16x8* wt1p = (const f16x8*)wt1a;
    // register-resident portion: q = 0..QREG-1
    #pragma unroll
    for (int jc = 0; jc < QREG / 4; ++jc) {
      f16x8 hv = hsh8[jc];
      f16x2 ha = __builtin_shufflevector(hv, hv, 0, 1);
      f16x2 hb = __builtin_shufflevector(hv, hv, 2, 3);
      f16x2 hc = __builtin_shufflevector(hv, hv, 4, 5);
      f16x2 hd = __builtin_shufflevector(hv, hv, 6, 7);
      acc0 = __builtin_amdgcn_fdot2(w0[4 * jc + 0], ha, acc0, false);
      acc0 = __builtin_amdgcn_fdot2(w0[4 * jc + 1], hb, acc0, false);
      acc0 = __builtin_amdgcn_fdot2(w0[4 * jc + 2], hc, acc0, false);
      acc0 = __builtin_amdgcn_fdot2(w0[4 * jc + 3], hd, acc0, false);
      acc1 = __builtin_amdgcn_fdot2(w1[4 * jc + 0], ha, acc1, false);
      acc1 = __builtin_amdgcn_fdot2(w1[4 * jc + 1], hb, acc1, false);
      acc1 = __builtin_amdgcn_fdot2(w1[4 * jc + 2], hc, acc1, false);
      acc1 = __builtin_amdgcn_fdot2(w1[4 * jc + 3], hd, acc1, false);
    }
    // streamed tail: q = QREG..127
    #pragma unroll
    for (int jc = 0; jc < QTL / 4; ++jc) {
      f16x8 hv = hsh8[QREG / 4 + jc];
      f16x8 wa = wt0p[jc];
      f16x8 wb = wt1p[jc];
      f16x2 ha = __builtin_shufflevector(hv, hv, 0, 1);
      f16x2 hb = __builtin_shufflevector(hv, hv, 2, 3);
      f16x2 hc = __builtin_shufflevector(hv, hv, 4, 5);
      f16x2 hd = __builtin_shufflevector(hv, hv, 6, 7);
      acc0 = __builtin_amdgcn_fdot2(__builtin_shufflevector(wa, wa, 0, 1), ha, acc0, false);
      acc0 = __builtin_amdgcn_fdot2(__builtin_shufflevector(wa, wa, 2, 3), hb, acc0, false);
      acc0 = __builtin_amdgcn_fdot2(__builtin_shufflevector(wa, wa, 4, 5), hc, acc0, false);
      acc0 = __builtin_amdgcn_fdot2(__builtin_shufflevector(wa, wa, 6, 7), hd, acc0, false);
      acc1 = __builtin_amdgcn_fdot2(__builtin_shufflevector(wb, wb, 0, 1), ha, acc1, false);
      acc1 = __builtin_amdgcn_fdot2(__builtin_shufflevector(wb, wb, 2, 3), hb, acc1, false);
      acc1 = __builtin_amdgcn_fdot2(__builtin_shufflevector(wb, wb, 4, 5), hc, acc1, false);
      acc1 = __builtin_amdgcn_fdot2(__builtin_shufflevector(wb, wb, 6, 7), hd, acc1, false);
    }
    gbuf[g0] = acc0;
    gbuf[g1] = acc1;
    __syncthreads();
    if (tt < CH) {
      float gi = gbuf[tt], gf = gbuf[CH + tt], gg = gbuf[2 * CH + tt], go = gbuf[3 * CH + tt];
      c = sigmf(gf) * c + sigmf(gi) * tanhf(gg);
      float h = sigmf(go) * tanhf(c);
      hsh[tt] = (_Float16)h;
      lo[(b * CS + t) * CH + tt] = h;
    }
    __syncthreads();
  }
}

// per (b,head): wS[i] = sum_{j>=1,adj} w_ij ; U[i][c] = sum_j w_ij * hint[j][c]   (rows i=1..127)
__global__ void k_U(const float* __restrict__ hint, const float* __restrict__ f1int,
                    const float* __restrict__ f2int, const int* __restrict__ adj,
                    float* __restrict__ U, float* __restrict__ wS) {
  int b = blockIdx.x >> 2, k = blockIdx.x & 3;
  int grp = threadIdx.x >> 6, c = threadIdx.x & 63;
  __shared__ float wbuf[4][128];
  const int adjb = b * CN * CN;
  for (int i = 1 + grp; i < 128; i += 4) {
    float f1 = f1int[k * 128 + (i - 1)];
    int j1 = 1 + c, j2 = 65 + c;
    float w1 = 0.f, w2 = 0.f;
    if (adj[adjb + i * CN + j1]) w1 = expf(leakyf(f1 + f2int[k * 128 + j1 - 1]));
    if (j2 < 128 && adj[adjb + i * CN + j2]) w2 = expf(leakyf(f1 + f2int[k * 128 + j2 - 1]));
    wbuf[grp][c] = w1;
    wbuf[grp][64 + c] = w2;              // slot 127 (c=63) = 0
    float rs = wredf(w1 + w2);
    float acc = 0.f;
    for (int jj = 0; jj < 127; ++jj)     // jj = j-1
      acc += wbuf[grp][jj] * hint[(k * 128 + jj) * CGH + c];
    if (c == 0) wS[(b * 4 + k) * 128 + i] = rs;
    U[((b * 4 + k) * 128 + i) * CGH + c] = acc;
  }
}

// htok[m, k*64+c] = lo[m,:] . Wh[k][:,c];  f1tok/f2tok[m,k] reductions
__global__ void k_htok(const float* __restrict__ lo, const float* __restrict__ Wh,
                       const float* __restrict__ ah, float* __restrict__ htok,
                       float* __restrict__ f1tok, float* __restrict__ f2tok) {
  __shared__ float ls[8][CH];
  int m0 = blockIdx.x * 8;
  int tid = threadIdx.x;
  int k = tid >> 6, c = tid & 63;
  for (int idx = tid; idx < 8 * CH; idx += 256) {
    int r = idx >> 8, d = idx & 255;
    ls[r][d] = lo[(m0 + r) * CH + d];
  }
  __syncthreads();
  float acc[8];
  #pragma unroll
  for (int r = 0; r < 8; ++r) acc[r] = 0.f;
  #pragma unroll 4
  for (int d = 0; d < CH; ++d) {
    float w = Wh[(k * CH + d) * CGH + c];
    #pragma unroll
    for (int r = 0; r < 8; ++r) acc[r] += w * ls[r][d];
  }
  float a1 = ah[k * 128 + c], a2 = ah[k * 128 + 64 + c];
  #pragma unroll
  for (int r = 0; r < 8; ++r) {
    htok[(m0 + r) * CH + tid] = acc[r];
    float r1 = wredf(acc[r] * a1);
    float r2 = wredf(acc[r] * a2);
    if (c == 0) { f1tok[(m0 + r) * CNH + k] = r1; f2tok[(m0 + r) * CNH + k] = r2; }
  }
}

// Per-token fused GAT layer-2 + logits, two-pass (no x1 LDS tile), adjacency-pruned.
__global__ __launch_bounds__(256) void k_perm2(
    const float* __restrict__ lo, const float* __restrict__ htok,
    const float* __restrict__ f1tok, const float* __restrict__ f2tok,
    const float* __restrict__ hint, const float* __restrict__ f1int,
    const float* __restrict__ f2int, const float* __restrict__ U,
    const float* __restrict__ wS, const float* __restrict__ woao1,
    const float* __restrict__ woao2, const int* __restrict__ adj,
    const float* __restrict__ Wo, const float* __restrict__ Wl,
    const float* __restrict__ bl, const int* __restrict__ seq_lens,
    float* __restrict__ out) {
  int m = blockIdx.x;
  int b = m >> 6, s = m & 63;
  int tid = threadIdx.x;
  int k = tid >> 6, c = tid & 63;

  __shared__ float ht[CH];
  __shared__ float s1[CNH][CN];
  __shared__ float s2[CNH][CN];
  __shared__ float w0[CNH][CN];
  __shared__ float x10[CH];
  __shared__ float f22[CN];
  __shared__ float w2s[CN];
  __shared__ float ybuf[CH];
  __shared__ float gbuf[CH];
  __shared__ float part[2][CV];
  __shared__ int   list[CN];
  __shared__ int   cnt;
  __shared__ float f12s, f220s, den2s;

  const int adjb = b * CN * CN;
  ht[tid] = htok[m * CH + tid];
  float f1t = f1tok[m * CNH + k];
  float f2t = f2tok[m * CNH + k];

  if (k == 0) {
    int j1 = 1 + c;
    int j2 = 65 + c;
    bool fl1 = adj[adjb + j1] != 0;
    bool fl2 = (j2 < CN) && (adj[adjb + j2] != 0);
    unsigned long long b1 = __ballot(fl1);
    unsigned long long b2 = __ballot(fl2);
    unsigned long long below = (1ull << c) - 1ull;
    int n1 = __popcll(b1);
    if (fl1) list[__popcll(b1 & below)] = j1;
    if (fl2) list[n1 + __popcll(b2 & below)] = j2;
    if (c == 0) cnt = n1 + __popcll(b2);
  }

  for (int idx = tid; idx < CNH * CN; idx += 256) {
    int k2 = idx >> 7, i = idx & 127;
    if (i == 0) continue;
    float t0 = 0.f;
    if (adj[adjb + i * CN]) t0 = expf(leakyf(f1int[k2 * 128 + i - 1] + f2tok[m * CNH + k2]));
    float rd = 1.f / (wS[(b * 4 + k2) * 128 + i] + t0);
    s1[k2][i] = rd;
    s2[k2][i] = t0 * rd;
  }

  float den0;
  {
    int j1 = c, j2 = c + 64;
    float e1 = leakyf(f1t + (j1 == 0 ? f2t : f2int[k * 128 + j1 - 1]));
    float wj1 = adj[adjb + j1] ? expf(e1) : 0.f;
    float e2 = leakyf(f1t + f2int[k * 128 + j2 - 1]);
    float wj2 = adj[adjb + j2] ? expf(e2) : 0.f;
    w0[k][j1] = wj1;
    w0[k][j2] = wj2;
    den0 = wredf(wj1 + wj2);
  }
  __syncthreads();
  const int na = cnt;

  {
    float acc = w0[k][0] * ht[tid];
    #pragma unroll 4
    for (int l = 0; l < na; ++l) {
      int j = list[l];
      acc += w0[k][j] * hint[(k * 128 + j - 1) * CGH + c];
    }
    x10[tid] = eluf(acc / den0);
  }
  __syncthreads();

  if (k == 0) {
    float p = x10[c] * woao1[c] + x10[c + 64] * woao1[c + 64]
            + x10[c + 128] * woao1[c + 128] + x10[c + 192] * woao1[c + 192];
    p = wredf(p);
    if (c == 0) f12s = p;
  }
  if (k == 1) {
    float p = x10[c] * woao2[c] + x10[c + 64] * woao2[c + 64]
            + x10[c + 128] * woao2[c + 128] + x10[c + 192] * woao2[c + 192];
    p = wredf(p);
    if (c == 0) f220s = p;
  }
  for (int l = k; l < na; l += 4) {
    int j = list[l];
    float p = 0.f;
    #pragma unroll
    for (int kk = 0; kk < 4; ++kk) {
      float u = U[((b * 4 + kk) * 128 + j) * CGH + c];
      float val = eluf(u * s1[kk][j] + s2[kk][j] * ht[kk * 64 + c]);
      p += val * woao2[kk * 64 + c];
    }
    p = wredf(p);
    if (c == 0) f22[l] = p;
  }
  __syncthreads();

  float w20 = expf(leakyf(f12s + f220s));
  if (tid < na) w2s[tid] = expf(leakyf(f12s + f22[tid]));
  __syncthreads();
  if (k == 0) {
    float v = (c < na ? w2s[c] : 0.f) + (c + 64 < na ? w2s[c + 64] : 0.f);
    v = wredf(v);
    if (c == 0) den2s = v + w20;
  }

  {
    float yacc = w20 * x10[tid];
    #pragma unroll 4
    for (int l = 0; l < na; ++l) {
      int j = list[l];
      float u = U[((b * 4 + k) * 128 + j) * CGH + c];
      float val = eluf(u * s1[k][j] + s2[k][j] * ht[tid]);
      yacc += w2s[l] * val;
    }
    ybuf[tid] = yacc;
  }
  __syncthreads();

  float hacc = 0.f;
  #pragma unroll 8
  for (int kk = 0; kk < CH; ++kk) hacc += ybuf[kk] * Wo[kk * CH + tid];
  float g = eluf(hacc / den2s) + lo[m * CH + tid];
  gbuf[tid] = g;
  __syncthreads();

  {
    int col = tid & 127, hh = tid >> 7;
    float acc = 0.f;
    #pragma unroll 8
    for (int cc = hh * 128; cc < hh * 128 + 128; ++cc) acc += gbuf[cc] * Wl[cc * CV + col];
    part[hh][col] = acc;
  }
  __syncthreads();
  if (tid < CV) {
    float r = part[0][tid] + part[1][tid] + bl[tid];
    out[m * CV + tid] = (s < seq_lens[b]) ? r : 0.f;
  }
}

}  // namespace

extern "C" void kernel_launch(void* const* d_in, const int* in_sizes, int n_in,
                              void* d_out, int out_size, void* d_ws, size_t ws_size,
                              hipStream_t stream) {
  const float* hidden   = (const float*)d_in[0];
  const int*   seq_lens = (const int*)d_in[1];
  const int*   forced   = (const int*)d_in[2];
  const int*   adj      = (const int*)d_in[3];
  const float* intent   = (const float*)d_in[4];
  const float* emb      = (const float*)d_in[5];
  const float* initt    = (const float*)d_in[6];
  const float* W_ih     = (const float*)d_in[7];
  const float* W_hh     = (const float*)d_in[8];
  const float* b_ih     = (const float*)d_in[9];
  const float* b_hh     = (const float*)d_in[10];
  const float* Wh       = (const float*)d_in[11];
  const float* ah       = (const float*)d_in[12];
  const float* Wo       = (const float*)d_in[13];
  const float* ao       = (const float*)d_in[14];
  const float* Wl       = (const float*)d_in[15];
  const float* bl       = (const float*)d_in[16];
  float* out = (float*)d_out;

  float* ws    = (float*)d_ws;
  float* x     = ws;                       // 2048*384
  float* WpF   = x + CM * CDX;             // QREG*1024 f16x2 slots
  float* WtF   = WpF + QREG * CG;          // 1024*QTL f16x2 slots
  float* xg    = WtF + CG * QTL;           // 2048*1024
  float* lo    = xg + CM * CG;             // 2048*256
  float* htok  = lo + CM * CH;             // 2048*256
  float* f1tok = htok + CM * CH;           // 2048*4
  float* f2tok = f1tok + CM * CNH;         // 2048*4
  float* hint  = f2tok + CM * CNH;         // 4*128*64
  float* f1int = hint + CNH * 128 * CGH;   // 4*128
  float* f2int = f1int + CNH * 128;        // 4*128
  float* U     = f2int + CNH * 128;        // 32*4*128*64
  float* wS    = U + CB * CNH * 128 * CGH; // 32*4*128
  float* woao1 = wS + CB * CNH * 128;      // 256
  float* woao2 = woao1 + CH;               // 256
  f16x2* Wp    = (f16x2*)WpF;
  f16x2* Wt    = (f16x2*)WtF;

  k_build_x<<<(CM * CDX + 255) / 256, 256, 0, stream>>>(hidden, forced, emb, initt, x);
  k_whh_pack<<<CG / 64, 256, 0, stream>>>(W_hh, Wp, Wt);
  k_hint<<<CNH * 127, 64, 0, stream>>>(intent, Wh, ah, hint, f1int, f2int);
  k_woao<<<1, 512, 0, stream>>>(Wo, ao, woao1, woao2);
  k_xg2<<<CM / 8, 256, 0, stream>>>(x, W_ih, b_ih, b_hh, xg);
  k_U<<<CB * CNH, 256, 0, stream>>>(hint, f1int, f2int, adj, U, wS);
  k_lstm4<<<CB, 512, 0, stream>>>(xg, Wp, Wt, lo);
  k_htok<<<CM / 8, 256, 0, stream>>>(lo, Wh, ah, htok, f1tok, f2tok);
  k_perm2<<<CM, 256, 0, stream>>>(lo, htok, f1tok, f2tok, hint, f1int, f2int,
                                  U, wS, woao1, woao2, adj, Wo, Wl, bl, seq_lens, out);
}